// Round 4
// baseline (209.671 us; speedup 1.0000x reference)
//
#include <hip/hip_runtime.h>
#include <hip/hip_bf16.h>

typedef __attribute__((ext_vector_type(8))) short short8;
typedef __attribute__((ext_vector_type(4))) short short4v;
typedef __attribute__((ext_vector_type(4))) float float4v;
typedef __attribute__((ext_vector_type(16))) float float16v;

static __device__ __forceinline__ unsigned short f2bf(float f) {
    unsigned u = __float_as_uint(f);
    unsigned r = (u + 0x7FFF + ((u >> 16) & 1)) >> 16;  // RNE
    return (unsigned short)r;
}

// ---------------------------------------------------------------------------
// ONE prep kernel (R7 version — known good).
//  [0,8)     : K1b[co][k64] bf16 (DCLS gather, conv1 B-operand layout)
//  [8,208)   : Kt[kk][co][ci] bf16 (DCLS gather, conv2 B-operand layout)
//  [208,404) : fc1w fp32 -> w1b bf16 (native (128,3136) layout)
// ---------------------------------------------------------------------------
__global__ __launch_bounds__(256) void prep_all(
    const float* __restrict__ w1, const float* __restrict__ p1,
    const float* __restrict__ w2, const float* __restrict__ p2,
    const float* __restrict__ fc1w,
    unsigned short* __restrict__ K1b,   // (32,64)
    unsigned short* __restrict__ Kt,    // (25,64,32)
    unsigned short* __restrict__ w1b) { // (128,3136)
    const int blk = blockIdx.x;
    const int t = threadIdx.x;

    if (blk < 8) {
        // conv1 weights, B-layout: K1b[co][k], k = wr*8 + kx (zero-padded taps)
        int cell = blk * 256 + t;          // 0..2047
        int co = cell >> 6;
        int k = cell & 63;
        int wr = k >> 3;
        int kx = k & 7;
        float acc = 0.f;
        if (wr < 5 && kx < 5) {
#pragma unroll 8
            for (int kc = 0; kc < 16; ++kc) {
                float wv = w1[co * 16 + kc];
                float pa = p1[co * 16 + kc];
                float pb = p1[512 + co * 16 + kc];
                float pos1 = fminf(fmaxf(pa, -2.f), 2.f) + 2.f;
                float pos2 = fminf(fmaxf(pb, -2.f), 2.f) + 2.f;
                int i1 = (int)floorf(pos1);
                int i2 = (int)floorf(pos2);
                float r1 = pos1 - (float)i1;
                float r2 = pos2 - (float)i2;
                float c = 0.f;
                if (i1 == wr && i2 == kx) c += (1.f - r1) * (1.f - r2);
                if (i1 + 1 == wr && i2 == kx) c += r1 * (1.f - r2);
                if (i1 == wr && i2 + 1 == kx) c += (1.f - r1) * r2;
                if (i1 + 1 == wr && i2 + 1 == kx) c += r1 * r2;
                acc += wv * c;
            }
        }
        K1b[cell] = f2bf(acc);
    } else if (blk < 208) {
        int cell = (blk - 8) * 256 + t;    // 0..51199
        int kk = cell >> 11;
        int co = (cell >> 5) & 63;
        int ci = cell & 31;
        int ky = kk / 5;
        int kx = kk - 5 * ky;
        const int base = (co * 32 + ci) * 32;
        float acc = 0.f;
#pragma unroll 8
        for (int kc = 0; kc < 32; ++kc) {
            float wv = w2[base + kc];
            float pa = p2[base + kc];
            float pb = p2[65536 + base + kc];
            float pos1 = fminf(fmaxf(pa, -2.f), 2.f) + 2.f;
            float pos2 = fminf(fmaxf(pb, -2.f), 2.f) + 2.f;
            int i1 = (int)floorf(pos1);
            int i2 = (int)floorf(pos2);
            float r1 = pos1 - (float)i1;
            float r2 = pos2 - (float)i2;
            float c = 0.f;
            if (i1 == ky && i2 == kx) c += (1.f - r1) * (1.f - r2);
            if (i1 + 1 == ky && i2 == kx) c += r1 * (1.f - r2);
            if (i1 == ky && i2 + 1 == kx) c += (1.f - r1) * r2;
            if (i1 + 1 == ky && i2 + 1 == kx) c += r1 * r2;
            acc += wv * c;
        }
        Kt[cell] = f2bf(acc);
    } else {
        int i8 = ((blk - 208) * 256 + t) * 8;  // < 401408 exactly (196 blocks)
        float4 v0 = *(const float4*)(fc1w + i8);
        float4 v1 = *(const float4*)(fc1w + i8 + 4);
        short8 o = {(short)f2bf(v0.x), (short)f2bf(v0.y), (short)f2bf(v0.z),
                    (short)f2bf(v0.w), (short)f2bf(v1.x), (short)f2bf(v1.y),
                    (short)f2bf(v1.z), (short)f2bf(v1.w)};
        *(short8*)(w1b + i8) = o;
    }
}

// ---------------------------------------------------------------------------
// Fused conv. conv1: 16x16x32 MFMA, 7x7 tiles of 4x4 px (R7-validated).
// conv2: 32x32x16 MFMA — wave owns pooled rows {2wv, 2wv+1}; m = 4*pX + inq.
// R13: full 1-tap read-ahead. R12's tap loop still had a serial lgkmcnt(0)
//   stall (frags read AFTER the barrier, right before their MFMAs), and the
//   (256,4) reg cap (124/128 used) forbade read-ahead -- while occupancy
//   showed only 3 blocks/CU resident anyway (4x40960 = exactly 163840; driver
//   reservation evicts the 4th). So: accept 3 blocks/CU, spend the registers.
//   - KtS is now a 3-buffer ring: tap k+2 staged while tap k computes, so
//     tap k+1's wf frags are readable DURING tap k (not gated by its barrier).
//   - Ping-pong frag regs (static kk&1 indexing): all 8 frag reads for tap
//     k+1 issue before tap k's MFMA cluster => MFMA waits on nothing.
//   - s_setprio(1) around the MFMA cluster (block drift = role diversity).
// LDS 44160 B; __launch_bounds__(256,3) (cap 170; ~100 VGPR + 64 AGPR).
// ---------------------------------------------------------------------------
__global__ __launch_bounds__(256, 3) void fused_conv_mfma(
    const float* __restrict__ x,             // (B,1,28,28) fp32
    const unsigned short* __restrict__ K1b,  // (32,64)
    const unsigned short* __restrict__ Kt,   // (25,64,32)
    const float* __restrict__ b1,
    const float* __restrict__ b2,
    unsigned short* __restrict__ h2) {       // (B,3136) bf16
    __shared__ __align__(16) unsigned short h1p[18 * 20 * 40];  // [yy][xx][ci(+pad)]
    // union region: conv1 uses sm4(5104)+sm_xb(784) = 5888; conv2 reuses as
    // KtS 3-buffer ring: 3 x 64 rows x 40 shorts = 7680 sh = 15360 B
    __shared__ __align__(16) unsigned short smu[7680];

    unsigned short* sm4 = smu;            // [4*29*44]
    unsigned short* sm_xb = smu + 5104;   // [784]
    unsigned short* KtS = smu;            // [3][64*40]

    const int b = blockIdx.x;
    const int tid = threadIdx.x;
    const int lane = tid & 63;
    const int wv = tid >> 6;
    const int n16 = lane & 15;
    const int cig = lane >> 4;

    // conv1 A-side m-mapping (4x4 tile): quad + in-quad
    const int yi = 2 * (n16 >> 3) + ((n16 >> 1) & 1);  // 0..3
    const int xi = 2 * ((n16 >> 2) & 1) + (n16 & 1);   // 0..3
    const int pYo = cig >> 1, pXo = cig & 1;           // conv1 D pooled offsets

    // conv2 lane decode (32x32x16): m = lane&31 -> (pX slot, dy, dx); h = k-group
    const int mq = lane & 31;
    const int Qx = mq >> 2;          // pX slot 0..7
    const int dy2 = (mq >> 1) & 1;
    const int dx2 = mq & 1;
    const int hh = lane >> 5;        // k-group; also output pX parity

    // staging decode: granule g = wv*64+lane covers shorts [8g, 8g+8) of the
    // 2048-short Kt[kk] tile; dest row g>>2 (stride 40), col (g&3)*8
    const int g = wv * 64 + lane;
    const int stg_dst = (g >> 2) * 40 + (g & 3) * 8;
    const unsigned short* stg_src = Kt + g * 8;   // + kk*2048

    // 1) zero h1p (borders + ci-pads must be 0) + stage image as bf16
    for (int t = tid; t < 1800; t += 256) ((uint4*)h1p)[t] = uint4{0, 0, 0, 0};
    {
        const float* xb = x + (size_t)b * 784;
        for (int t = tid; t < 784; t += 256) sm_xb[t] = f2bf(xb[t]);
    }
    __syncthreads();

    // 2) build 4 shifted copies (copy s pos p = pixel col p+s-4; row 28 = zeros)
    if (tid < 116) {
        int s = tid / 29;
        int r = tid - s * 29;
        unsigned short* dst = sm4 + (s * 29 + r) * 44;
        bool rok = r < 28;
#pragma unroll
        for (int g2 = 0; g2 < 11; ++g2) {
            short4v v;
#pragma unroll
            for (int e = 0; e < 4; ++e) {
                int c = g2 * 4 + e + s - 4;
                v[e] = (short)((rok && (unsigned)c < 28u) ? sm_xb[r * 28 + c]
                                                          : (unsigned short)0);
            }
            *(short4v*)(dst + g2 * 4) = v;
        }
    }

    // conv1 weight B-frags (register-resident) + biases
    short8 bw[2][2];
    float bias1[2], bias2n[2];
#pragma unroll
    for (int cot = 0; cot < 2; ++cot) {
#pragma unroll
        for (int h = 0; h < 2; ++h)
            bw[cot][h] = *(const short8*)(K1b + (cot * 16 + n16) * 64 + h * 32 + cig * 8);
        bias1[cot] = b1[cot * 16 + n16];
    }
#pragma unroll
    for (int nt = 0; nt < 2; ++nt) bias2n[nt] = b2[nt * 32 + mq];

    // per-lane constant part of sm4 address (4tX is always 0 mod 4)
    const int s1 = (xi + 2) & 3;
    const int pb1 = (xi + 2) & ~3;
    const unsigned short* a1base = sm4 + s1 * (29 * 44) + pb1;

    __syncthreads();

    // 3) conv1: 49 tiles (7x7 of 4x4 px), wave-split; 4 MFMA + 2 stores/tile
    for (int i = 0; i < 13; ++i) {
        int t = wv + 4 * i;
        if (t < 49) {
            int tY = t / 7, tX = t - 7 * tY;
            const unsigned short* ab = a1base + 4 * tX;
            int r0 = 4 * tY + yi - 2 + cig;           // window rows 0..3
            int r1 = r0 + 4;                          // window rows 4..7
            int rr0 = ((unsigned)r0 < 28u) ? r0 : 28; // 28 = zero row
            int rr1 = ((unsigned)r1 < 28u) ? r1 : 28;
            short4v lo0 = *(const short4v*)(ab + rr0 * 44);
            short4v hi0 = *(const short4v*)(ab + rr0 * 44 + 4);
            short4v lo1 = *(const short4v*)(ab + rr1 * 44);
            short4v hi1 = *(const short4v*)(ab + rr1 * 44 + 4);
            short8 af0 = {lo0[0], lo0[1], lo0[2], lo0[3], hi0[0], hi0[1], hi0[2], hi0[3]};
            short8 af1 = {lo1[0], lo1[1], lo1[2], lo1[3], hi1[0], hi1[1], hi1[2], hi1[3]};
            int pY = 2 * tY + pYo, pX = 2 * tX + pXo;
#pragma unroll
            for (int cot = 0; cot < 2; ++cot) {
                float4v acc = {0.f, 0.f, 0.f, 0.f};
                acc = __builtin_amdgcn_mfma_f32_16x16x32_bf16(af0, bw[cot][0], acc, 0, 0, 0);
                acc = __builtin_amdgcn_mfma_f32_16x16x32_bf16(af1, bw[cot][1], acc, 0, 0, 0);
                float v = fmaxf(fmaxf(acc[0], acc[1]), fmaxf(acc[2], acc[3]));
                v = fmaxf(v + bias1[cot], 0.f);
                h1p[((pY + 2) * 20 + (pX + 2)) * 40 + cot * 16 + n16] = f2bf(v);
            }
        }
    }

    // 4) conv2: 32x32x16. Wave -> pooled rows pY = 2wv+mt; A lane m -> (Qx,dy,dx);
    //    k = ci = khalf*16 + hh*8 + j. Phantom x/y clamped, discarded at write.
    int x2 = 2 * Qx + dx2;
    if (x2 > 13) x2 = 13;
    int aoff[2][2];
    int pYv[2];
#pragma unroll
    for (int mt = 0; mt < 2; ++mt) {
        int pY = 2 * wv + mt;            // 0..7
        int y2 = 2 * pY + dy2;           // 0..15
        if (y2 > 13) y2 = 13;
        pYv[mt] = pY;
#pragma unroll
        for (int kh2 = 0; kh2 < 2; ++kh2)
            aoff[mt][kh2] = (y2 * 20 + x2) * 40 + kh2 * 16 + hh * 8;
    }

    float16v acc2[2][2];  // [mt][nt] = 64 AGPR
#pragma unroll
    for (int mt = 0; mt < 2; ++mt)
#pragma unroll
        for (int nt = 0; nt < 2; ++nt)
#pragma unroll
            for (int e = 0; e < 16; ++e) acc2[mt][nt][e] = 0.f;

    // wf read base within a KtS buffer: row = nt*32+mq (stride 40), col kh2*16+hh*8
    const int wbase = mq * 40 + hh * 8;

    // --- prologue: stage taps 0,1 into bufs 0,1; read tap-0 frags into set 0
    short8 stg0 = *(const short8*)(stg_src);
    short8 stg1 = *(const short8*)(stg_src + 2048);
    __syncthreads();                       // conv1 done (h1p written, sm4 dead)
    *(short8*)(KtS + stg_dst) = stg0;               // buf 0 = tap 0
    *(short8*)(KtS + 2560 + stg_dst) = stg1;        // buf 1 = tap 1
    __syncthreads();

    short8 wfp[2][2][2];   // [set][nt][khalf]
    short8 afp[2][2][2];   // [set][mt][khalf]
#pragma unroll
    for (int nt = 0; nt < 2; ++nt)
#pragma unroll
        for (int q = 0; q < 2; ++q)
            wfp[0][nt][q] = *(const short8*)(KtS + nt * 1280 + wbase + q * 16);
#pragma unroll
    for (int mt = 0; mt < 2; ++mt)
#pragma unroll
        for (int q = 0; q < 2; ++q)
            afp[0][mt][q] = *(const short8*)(h1p + aoff[mt][q]);

#pragma unroll
    for (int kk = 0; kk < 25; ++kk) {
        const int cs = kk & 1;          // compile-time after full unroll
        const int ns = cs ^ 1;
        short8 stg;
        if (kk < 23) stg = *(const short8*)(stg_src + (kk + 2) * 2048);

        if (kk < 24) {                  // read-ahead tap k+1 frags
            const int kn = kk + 1;
            const int ky = kn / 5;
            const int kx = kn - 5 * ky;
            const int soff = (ky * 20 + kx) * 40;
            const int nbuf = (kn % 3) * 2560;
#pragma unroll
            for (int nt = 0; nt < 2; ++nt)
#pragma unroll
                for (int q = 0; q < 2; ++q)
                    wfp[ns][nt][q] = *(const short8*)(KtS + nbuf + nt * 1280 +
                                                      wbase + q * 16);
#pragma unroll
            for (int mt = 0; mt < 2; ++mt)
#pragma unroll
                for (int q = 0; q < 2; ++q)
                    afp[ns][mt][q] = *(const short8*)(h1p + aoff[mt][q] + soff);
        }

        __builtin_amdgcn_sched_barrier(0);  // reads(k+1) stay above mfma(k)
        __builtin_amdgcn_s_setprio(1);
#pragma unroll
        for (int mt = 0; mt < 2; ++mt)
#pragma unroll
            for (int nt = 0; nt < 2; ++nt) {
                acc2[mt][nt] = __builtin_amdgcn_mfma_f32_32x32x16_bf16(
                    afp[cs][mt][0], wfp[cs][nt][0], acc2[mt][nt], 0, 0, 0);
                acc2[mt][nt] = __builtin_amdgcn_mfma_f32_32x32x16_bf16(
                    afp[cs][mt][1], wfp[cs][nt][1], acc2[mt][nt], 0, 0, 0);
            }
        __builtin_amdgcn_s_setprio(0);
        __builtin_amdgcn_sched_barrier(0);  // mfma(k) stays above write(k+2)

        if (kk < 23) *(short8*)(KtS + ((kk + 2) % 3) * 2560 + stg_dst) = stg;
        if (kk < 24) __syncthreads();
    }

    // epilogue: reg-quad g holds rows 8g+4hh+{0..3} = pool quad pX = 2g+hh
    unsigned short* outb = h2 + (size_t)b * 3136;
#pragma unroll
    for (int mt = 0; mt < 2; ++mt) {
        if (pYv[mt] < 7) {
#pragma unroll
            for (int nt = 0; nt < 2; ++nt) {
#pragma unroll
                for (int g2 = 0; g2 < 4; ++g2) {
                    int pX = 2 * g2 + hh;
                    float v = fmaxf(fmaxf(acc2[mt][nt][4 * g2], acc2[mt][nt][4 * g2 + 1]),
                                    fmaxf(acc2[mt][nt][4 * g2 + 2], acc2[mt][nt][4 * g2 + 3]));
                    v = fmaxf(v + bias2n[nt], 0.f);
                    if (pX < 7)
                        outb[(nt * 32 + mq) * 49 + pYv[mt] * 7 + pX] = f2bf(v);
                }
            }
        }
    }
}

// ---------------------------------------------------------------------------
// FC1 MFMA, 64-row blocks (R8/R9 version): partials[kh](B,128) = A @ W^T slice
// kh (K-split 7). A-tile staged in LDS; waves split N. Plain stores.
__global__ __launch_bounds__(256) void fc1_mfma(
    const unsigned short* __restrict__ A,
    const unsigned short* __restrict__ Wb,
    float* __restrict__ part, size_t PB) {  // PB = B*128
    __shared__ __align__(16) unsigned short As[64 * 72];  // stride 72 breaks banks
    const int blk = blockIdx.x;
    const int kh = blk % 7;
    const int m0 = (blk / 7) * 64;
    const int tid = threadIdx.x;
    const int wv = tid >> 6;
    const int lane = tid & 63;
    const int n16 = lane & 15;
    const int cig = lane >> 4;

    float4v acc[4][2];  // [mt][j]
#pragma unroll
    for (int mt = 0; mt < 4; ++mt)
#pragma unroll
        for (int j = 0; j < 2; ++j) acc[mt][j] = float4v{0.f, 0.f, 0.f, 0.f};

    for (int it = 0; it < 7; ++it) {
        int k0 = kh * 448 + it * 64;
        __syncthreads();
#pragma unroll
        for (int i = 0; i < 2; ++i) {
            int p = tid + 256 * i;         // 0..511 = 64 rows x 8 k-octs
            int r = p >> 3, ko = (p & 7) * 8;
            *(short8*)(As + r * 72 + ko) =
                *(const short8*)(A + (size_t)(m0 + r) * 3136 + k0 + ko);
        }
        __syncthreads();
#pragma unroll
        for (int h = 0; h < 2; ++h) {
            short8 af[4];
#pragma unroll
            for (int mt = 0; mt < 4; ++mt)
                af[mt] = *(const short8*)(As + (mt * 16 + n16) * 72 + h * 32 + cig * 8);
            short8 wf[2];
#pragma unroll
            for (int j = 0; j < 2; ++j)
                wf[j] = *(const short8*)(Wb + (size_t)((wv * 2 + j) * 16 + n16) * 3136 +
                                         k0 + h * 32 + cig * 8);
#pragma unroll
            for (int mt = 0; mt < 4; ++mt)
#pragma unroll
                for (int j = 0; j < 2; ++j)
                    acc[mt][j] = __builtin_amdgcn_mfma_f32_16x16x32_bf16(
                        af[mt], wf[j], acc[mt][j], 0, 0, 0);
        }
    }
    float* o = part + (size_t)kh * PB;
#pragma unroll
    for (int mt = 0; mt < 4; ++mt)
#pragma unroll
        for (int j = 0; j < 2; ++j)
#pragma unroll
            for (int r = 0; r < 4; ++r) {
                int row = m0 + mt * 16 + cig * 4 + r;
                o[(size_t)row * 128 + (wv * 2 + j) * 16 + n16] = acc[mt][j][r];
            }
}

// FC2 row-centric: thread (r,q) builds relu(sum of 7 partials + b1) for its
// 16-k slice ONCE (part read 1x, not 10x), dots vs all 10 W rows from LDS,
// shfl-xor(1,2,4) k-reduce. Block = 32 rows; grid B/32.
__global__ __launch_bounds__(256) void fc2_kernel(
    const float* __restrict__ part, size_t PB,
    const float* __restrict__ fc1b,
    const float* __restrict__ W, const float* __restrict__ bias,
    float* __restrict__ out) {
    __shared__ float smW[10 * 132];
    __shared__ float smB1[128];
    __shared__ float smB[10];
    int t = threadIdx.x;
    for (int i = t; i < 1280; i += 256) {
        int n = i >> 7, k = i & 127;
        smW[n * 132 + k] = W[i];
    }
    if (t < 128) smB1[t] = fc1b[t];
    if (t < 10) smB[t] = bias[t];
    __syncthreads();
    const int r = t >> 3;          // 0..31 (batch row in block)
    const int q = t & 7;           // 16-float k-slice
    const size_t b = (size_t)blockIdx.x * 32 + r;
    const float* pb = part + b * 128 + q * 16;

    float rv[16];
#pragma unroll
    for (int c = 0; c < 4; ++c) {
        float4 s = *(const float4*)(pb + 4 * c);
#pragma unroll
        for (int j = 1; j < 7; ++j) {
            float4 pj = *(const float4*)(pb + (size_t)j * PB + 4 * c);
            s.x += pj.x; s.y += pj.y; s.z += pj.z; s.w += pj.w;
        }
        float4 bv = *(const float4*)(smB1 + q * 16 + 4 * c);
        rv[4 * c + 0] = fmaxf(s.x + bv.x, 0.f);
        rv[4 * c + 1] = fmaxf(s.y + bv.y, 0.f);
        rv[4 * c + 2] = fmaxf(s.z + bv.z, 0.f);
        rv[4 * c + 3] = fmaxf(s.w + bv.w, 0.f);
    }
    float acc[10];
#pragma unroll
    for (int n = 0; n < 10; ++n) {
        const float4* wr = (const float4*)(smW + n * 132 + q * 16);
        float a = 0.f;
#pragma unroll
        for (int c = 0; c < 4; ++c) {
            float4 w = wr[c];
            a += rv[4 * c] * w.x + rv[4 * c + 1] * w.y +
                 rv[4 * c + 2] * w.z + rv[4 * c + 3] * w.w;
        }
        acc[n] = a;
    }
#pragma unroll
    for (int n = 0; n < 10; ++n) {
        acc[n] += __shfl_xor(acc[n], 1);
        acc[n] += __shfl_xor(acc[n], 2);
        acc[n] += __shfl_xor(acc[n], 4);
    }
    if (q == 0) {
#pragma unroll
        for (int n = 0; n < 10; ++n) out[b * 10 + n] = acc[n] + smB[n];
    }
}

extern "C" void kernel_launch(void* const* d_in, const int* in_sizes, int n_in,
                              void* d_out, int out_size, void* d_ws, size_t ws_size,
                              hipStream_t stream) {
    const float* x    = (const float*)d_in[0];
    const float* w1   = (const float*)d_in[1];
    const float* p1   = (const float*)d_in[2];
    const float* b1   = (const float*)d_in[3];
    const float* w2   = (const float*)d_in[4];
    const float* p2   = (const float*)d_in[5];
    const float* b2   = (const float*)d_in[6];
    const float* fc1w = (const float*)d_in[7];
    const float* fc1b = (const float*)d_in[8];
    const float* fc2w = (const float*)d_in[9];
    const float* fc2b = (const float*)d_in[10];
    float* out = (float*)d_out;

    const int B = in_sizes[0] / 784;  // 4096

    float* ws = (float*)d_ws;
    unsigned short* Kt  = (unsigned short*)ws;             // 51200 sh = 25600 f
    unsigned short* K1b = (unsigned short*)(ws + 25600);   // 2048 sh = 1024 f
    unsigned short* w1b = (unsigned short*)(ws + 26624);   // 401408 sh = 200704 f
    unsigned short* h2b = (unsigned short*)(ws + 227328);  // B*3136 sh = B*1568 f
    float* fc1p = ws + 227328 + (size_t)B * 1568;          // 7*B*128 f

    prep_all<<<404, 256, 0, stream>>>(w1, p1, w2, p2, fc1w, K1b, Kt, w1b);
    fused_conv_mfma<<<B, 256, 0, stream>>>(x, K1b, Kt, b1, b2, h2b);
    fc1_mfma<<<(B / 64) * 7, 256, 0, stream>>>(h2b, w1b, fc1p, (size_t)B * 128);
    fc2_kernel<<<B / 32, 256, 0, stream>>>(fc1p, (size_t)B * 128,
                                           fc1b, fc2w, fc2b, out);
}

// Round 5
// 208.110 us; speedup vs baseline: 1.0075x; 1.0075x over previous
//
#include <hip/hip_runtime.h>
#include <hip/hip_bf16.h>

typedef __attribute__((ext_vector_type(8))) short short8;
typedef __attribute__((ext_vector_type(4))) short short4v;
typedef __attribute__((ext_vector_type(4))) float float4v;
typedef __attribute__((ext_vector_type(16))) float float16v;

static __device__ __forceinline__ unsigned short f2bf(float f) {
    unsigned u = __float_as_uint(f);
    unsigned r = (u + 0x7FFF + ((u >> 16) & 1)) >> 16;  // RNE
    return (unsigned short)r;
}

// ---------------------------------------------------------------------------
// ONE prep kernel.
//  [0,8)     : K1b[co][k64] bf16 (DCLS gather, conv1 B-operand layout)
//  [8,208)   : Kt bf16 in MFMA FRAGMENT ORDER [kk][nt][kh2][hh][mq][8]  (R14)
//              so conv2 wf reads are lane-contiguous 1KB L2 loads.
//  [208,404) : fc1w fp32 -> w1b bf16 (native (128,3136) layout)
// ---------------------------------------------------------------------------
__global__ __launch_bounds__(256) void prep_all(
    const float* __restrict__ w1, const float* __restrict__ p1,
    const float* __restrict__ w2, const float* __restrict__ p2,
    const float* __restrict__ fc1w,
    unsigned short* __restrict__ K1b,   // (32,64)
    unsigned short* __restrict__ Kt,    // (25,2,2,2,32,8) fragment order
    unsigned short* __restrict__ w1b) { // (128,3136)
    const int blk = blockIdx.x;
    const int t = threadIdx.x;

    if (blk < 8) {
        // conv1 weights, B-layout: K1b[co][k], k = wr*8 + kx (zero-padded taps)
        int cell = blk * 256 + t;          // 0..2047
        int co = cell >> 6;
        int k = cell & 63;
        int wr = k >> 3;
        int kx = k & 7;
        float acc = 0.f;
        if (wr < 5 && kx < 5) {
#pragma unroll 8
            for (int kc = 0; kc < 16; ++kc) {
                float wv = w1[co * 16 + kc];
                float pa = p1[co * 16 + kc];
                float pb = p1[512 + co * 16 + kc];
                float pos1 = fminf(fmaxf(pa, -2.f), 2.f) + 2.f;
                float pos2 = fminf(fmaxf(pb, -2.f), 2.f) + 2.f;
                int i1 = (int)floorf(pos1);
                int i2 = (int)floorf(pos2);
                float r1 = pos1 - (float)i1;
                float r2 = pos2 - (float)i2;
                float c = 0.f;
                if (i1 == wr && i2 == kx) c += (1.f - r1) * (1.f - r2);
                if (i1 + 1 == wr && i2 == kx) c += r1 * (1.f - r2);
                if (i1 == wr && i2 + 1 == kx) c += (1.f - r1) * r2;
                if (i1 + 1 == wr && i2 + 1 == kx) c += r1 * r2;
                acc += wv * c;
            }
        }
        K1b[cell] = f2bf(acc);
    } else if (blk < 208) {
        int cell = (blk - 8) * 256 + t;    // 0..51199
        int kk = cell >> 11;
        int co = (cell >> 5) & 63;
        int ci = cell & 31;
        int ky = kk / 5;
        int kx = kk - 5 * ky;
        const int base = (co * 32 + ci) * 32;
        float acc = 0.f;
#pragma unroll 8
        for (int kc = 0; kc < 32; ++kc) {
            float wv = w2[base + kc];
            float pa = p2[base + kc];
            float pb = p2[65536 + base + kc];
            float pos1 = fminf(fmaxf(pa, -2.f), 2.f) + 2.f;
            float pos2 = fminf(fmaxf(pb, -2.f), 2.f) + 2.f;
            int i1 = (int)floorf(pos1);
            int i2 = (int)floorf(pos2);
            float r1 = pos1 - (float)i1;
            float r2 = pos2 - (float)i2;
            float c = 0.f;
            if (i1 == ky && i2 == kx) c += (1.f - r1) * (1.f - r2);
            if (i1 + 1 == ky && i2 == kx) c += r1 * (1.f - r2);
            if (i1 == ky && i2 + 1 == kx) c += (1.f - r1) * r2;
            if (i1 + 1 == ky && i2 + 1 == kx) c += r1 * r2;
            acc += wv * c;
        }
        // fragment-order write: [kk][nt][kh2][hh][mq][j]
        int nt = co >> 5, mq = co & 31;
        int kh2 = ci >> 4, hh = (ci >> 3) & 1, jj = ci & 7;
        Kt[kk * 2048 + nt * 1024 + kh2 * 512 + hh * 256 + mq * 8 + jj] = f2bf(acc);
    } else {
        int i8 = ((blk - 208) * 256 + t) * 8;  // < 401408 exactly (196 blocks)
        float4 v0 = *(const float4*)(fc1w + i8);
        float4 v1 = *(const float4*)(fc1w + i8 + 4);
        short8 o = {(short)f2bf(v0.x), (short)f2bf(v0.y), (short)f2bf(v0.z),
                    (short)f2bf(v0.w), (short)f2bf(v1.x), (short)f2bf(v1.y),
                    (short)f2bf(v1.z), (short)f2bf(v1.w)};
        *(short8*)(w1b + i8) = o;
    }
}

// ---------------------------------------------------------------------------
// Fused conv. conv1: 16x16x32 MFMA, 7x7 tiles of 4x4 px (R7-validated).
// conv2: 32x32x16 MFMA — wave owns pooled rows {2wv, 2wv+1}; m = 4*pX + inq.
// R14: BARRIER-FREE conv2. Kt is pre-permuted to fragment order, so each
//   wave streams its own wf directly from L2 as lane-contiguous 1KB loads
//   (Kt + kk*2048 + nt*1024 + kh2*512 + lane*8). No LDS staging, no
//   __syncthreads in the tap loop (only the one conv1->conv2 barrier).
//   Per-tap LDS traffic drops 36KB -> 16KB per block (af only); the 25
//   barrier drains vanish. wf for tap k+1 is read-ahead into ping-pong
//   regs (static kk&1 indexing, the idiom that held in R11/R13); af is
//   read JIT from h1p (LDS, covered by MFMA + 3-wave TLP + wave drift).
//   setprio(1) around MFMA clusters arbitrates drifted waves (T5 regime).
// LDS 40576 B; __launch_bounds__(256,3): ~3 blocks/CU, reg cap 170.
// ---------------------------------------------------------------------------
__global__ __launch_bounds__(256, 3) void fused_conv_mfma(
    const float* __restrict__ x,             // (B,1,28,28) fp32
    const unsigned short* __restrict__ K1b,  // (32,64)
    const unsigned short* __restrict__ Kt,   // (25,2,2,2,32,8) fragment order
    const float* __restrict__ b1,
    const float* __restrict__ b2,
    unsigned short* __restrict__ h2) {       // (B,3136) bf16
    __shared__ __align__(16) unsigned short h1p[18 * 20 * 40];  // [yy][xx][ci(+pad)]
    __shared__ __align__(16) unsigned short sm4[4 * 29 * 44];   // 4 shifted copies; row 28 zero
    __shared__ __align__(16) unsigned short sm_xb[784];

    const int b = blockIdx.x;
    const int tid = threadIdx.x;
    const int lane = tid & 63;
    const int wv = tid >> 6;
    const int n16 = lane & 15;
    const int cig = lane >> 4;

    // conv1 A-side m-mapping (4x4 tile): quad + in-quad
    const int yi = 2 * (n16 >> 3) + ((n16 >> 1) & 1);  // 0..3
    const int xi = 2 * ((n16 >> 2) & 1) + (n16 & 1);   // 0..3
    const int pYo = cig >> 1, pXo = cig & 1;           // conv1 D pooled offsets

    // conv2 lane decode (32x32x16): m = lane&31 -> (pX slot, dy, dx); h = k-group
    const int mq = lane & 31;
    const int Qx = mq >> 2;          // pX slot 0..7
    const int dy2 = (mq >> 1) & 1;
    const int dx2 = mq & 1;
    const int hh = lane >> 5;        // k-group; also output pX parity

    // 1) zero h1p (borders + ci-pads must be 0) + stage image as bf16
    for (int t = tid; t < 1800; t += 256) ((uint4*)h1p)[t] = uint4{0, 0, 0, 0};
    {
        const float* xb = x + (size_t)b * 784;
        for (int t = tid; t < 784; t += 256) sm_xb[t] = f2bf(xb[t]);
    }
    __syncthreads();

    // 2) build 4 shifted copies (copy s pos p = pixel col p+s-4; row 28 = zeros)
    if (tid < 116) {
        int s = tid / 29;
        int r = tid - s * 29;
        unsigned short* dst = sm4 + (s * 29 + r) * 44;
        bool rok = r < 28;
#pragma unroll
        for (int g2 = 0; g2 < 11; ++g2) {
            short4v v;
#pragma unroll
            for (int e = 0; e < 4; ++e) {
                int c = g2 * 4 + e + s - 4;
                v[e] = (short)((rok && (unsigned)c < 28u) ? sm_xb[r * 28 + c]
                                                          : (unsigned short)0);
            }
            *(short4v*)(dst + g2 * 4) = v;
        }
    }

    // conv1 weight B-frags (register-resident) + biases
    short8 bw[2][2];
    float bias1[2], bias2n[2];
#pragma unroll
    for (int cot = 0; cot < 2; ++cot) {
#pragma unroll
        for (int h = 0; h < 2; ++h)
            bw[cot][h] = *(const short8*)(K1b + (cot * 16 + n16) * 64 + h * 32 + cig * 8);
        bias1[cot] = b1[cot * 16 + n16];
    }
#pragma unroll
    for (int nt = 0; nt < 2; ++nt) bias2n[nt] = b2[nt * 32 + mq];

    // per-lane constant part of sm4 address (4tX is always 0 mod 4)
    const int s1 = (xi + 2) & 3;
    const int pb1 = (xi + 2) & ~3;
    const unsigned short* a1base = sm4 + s1 * (29 * 44) + pb1;

    __syncthreads();

    // 3) conv1: 49 tiles (7x7 of 4x4 px), wave-split; 4 MFMA + 2 stores/tile
    for (int i = 0; i < 13; ++i) {
        int t = wv + 4 * i;
        if (t < 49) {
            int tY = t / 7, tX = t - 7 * tY;
            const unsigned short* ab = a1base + 4 * tX;
            int r0 = 4 * tY + yi - 2 + cig;           // window rows 0..3
            int r1 = r0 + 4;                          // window rows 4..7
            int rr0 = ((unsigned)r0 < 28u) ? r0 : 28; // 28 = zero row
            int rr1 = ((unsigned)r1 < 28u) ? r1 : 28;
            short4v lo0 = *(const short4v*)(ab + rr0 * 44);
            short4v hi0 = *(const short4v*)(ab + rr0 * 44 + 4);
            short4v lo1 = *(const short4v*)(ab + rr1 * 44);
            short4v hi1 = *(const short4v*)(ab + rr1 * 44 + 4);
            short8 af0 = {lo0[0], lo0[1], lo0[2], lo0[3], hi0[0], hi0[1], hi0[2], hi0[3]};
            short8 af1 = {lo1[0], lo1[1], lo1[2], lo1[3], hi1[0], hi1[1], hi1[2], hi1[3]};
            int pY = 2 * tY + pYo, pX = 2 * tX + pXo;
#pragma unroll
            for (int cot = 0; cot < 2; ++cot) {
                float4v acc = {0.f, 0.f, 0.f, 0.f};
                acc = __builtin_amdgcn_mfma_f32_16x16x32_bf16(af0, bw[cot][0], acc, 0, 0, 0);
                acc = __builtin_amdgcn_mfma_f32_16x16x32_bf16(af1, bw[cot][1], acc, 0, 0, 0);
                float v = fmaxf(fmaxf(acc[0], acc[1]), fmaxf(acc[2], acc[3]));
                v = fmaxf(v + bias1[cot], 0.f);
                h1p[((pY + 2) * 20 + (pX + 2)) * 40 + cot * 16 + n16] = f2bf(v);
            }
        }
    }

    // 4) conv2: 32x32x16. Wave -> pooled rows pY = 2wv+mt; A lane m -> (Qx,dy,dx);
    //    k = ci = khalf*16 + hh*8 + j. Phantom x/y clamped, discarded at write.
    int x2 = 2 * Qx + dx2;
    if (x2 > 13) x2 = 13;
    int aoff[2][2];
    int pYv[2];
#pragma unroll
    for (int mt = 0; mt < 2; ++mt) {
        int pY = 2 * wv + mt;            // 0..7
        int y2 = 2 * pY + dy2;           // 0..15
        if (y2 > 13) y2 = 13;
        pYv[mt] = pY;
#pragma unroll
        for (int kh2 = 0; kh2 < 2; ++kh2)
            aoff[mt][kh2] = (y2 * 20 + x2) * 40 + kh2 * 16 + hh * 8;
    }

    float16v acc2[2][2];  // [mt][nt] = 64 AGPR
#pragma unroll
    for (int mt = 0; mt < 2; ++mt)
#pragma unroll
        for (int nt = 0; nt < 2; ++nt)
#pragma unroll
            for (int e = 0; e < 16; ++e) acc2[mt][nt][e] = 0.f;

    // lane-const base: contiguous 1KB per (kk,nt,kh2) wf read from L2
    const unsigned short* KtL = Kt + lane * 8;

    // ping-pong wf read-ahead (global, ~200-400cy L2 latency hidden by one
    // full tap of MFMA + 3-wave TLP). Prologue load issues before the
    // conv1->conv2 barrier (no LDS dependence).
    short8 wfp[2][2][2];   // [set][nt][kh2]
#pragma unroll
    for (int nt = 0; nt < 2; ++nt)
#pragma unroll
        for (int q = 0; q < 2; ++q)
            wfp[0][nt][q] = *(const short8*)(KtL + nt * 1024 + q * 512);

    __syncthreads();   // conv1 h1p visible to all waves; ONLY barrier for conv2

#pragma unroll
    for (int kk = 0; kk < 25; ++kk) {
        const int cs = kk & 1;          // compile-time after full unroll
        const int ns = cs ^ 1;
        if (kk < 24) {                  // read-ahead tap k+1 wf (coalesced L2)
#pragma unroll
            for (int nt = 0; nt < 2; ++nt)
#pragma unroll
                for (int q = 0; q < 2; ++q)
                    wfp[ns][nt][q] = *(const short8*)(KtL + (kk + 1) * 2048 +
                                                      nt * 1024 + q * 512);
        }
        // af JIT from LDS
        const int ky = kk / 5;
        const int kx = kk - 5 * ky;
        const int soff = (ky * 20 + kx) * 40;
        short8 aff[2][2];
#pragma unroll
        for (int mt = 0; mt < 2; ++mt)
#pragma unroll
            for (int q = 0; q < 2; ++q)
                aff[mt][q] = *(const short8*)(h1p + aoff[mt][q] + soff);

        __builtin_amdgcn_sched_barrier(0);  // loads stay above mfma(k)
        __builtin_amdgcn_s_setprio(1);
#pragma unroll
        for (int mt = 0; mt < 2; ++mt)
#pragma unroll
            for (int nt = 0; nt < 2; ++nt) {
                acc2[mt][nt] = __builtin_amdgcn_mfma_f32_32x32x16_bf16(
                    aff[mt][0], wfp[cs][nt][0], acc2[mt][nt], 0, 0, 0);
                acc2[mt][nt] = __builtin_amdgcn_mfma_f32_32x32x16_bf16(
                    aff[mt][1], wfp[cs][nt][1], acc2[mt][nt], 0, 0, 0);
            }
        __builtin_amdgcn_s_setprio(0);
        __builtin_amdgcn_sched_barrier(0);  // mfma(k) stays above loads(k+1)
    }

    // epilogue: reg-quad g holds rows 8g+4hh+{0..3} = pool quad pX = 2g+hh
    unsigned short* outb = h2 + (size_t)b * 3136;
#pragma unroll
    for (int mt = 0; mt < 2; ++mt) {
        if (pYv[mt] < 7) {
#pragma unroll
            for (int nt = 0; nt < 2; ++nt) {
#pragma unroll
                for (int g2 = 0; g2 < 4; ++g2) {
                    int pX = 2 * g2 + hh;
                    float v = fmaxf(fmaxf(acc2[mt][nt][4 * g2], acc2[mt][nt][4 * g2 + 1]),
                                    fmaxf(acc2[mt][nt][4 * g2 + 2], acc2[mt][nt][4 * g2 + 3]));
                    v = fmaxf(v + bias2n[nt], 0.f);
                    if (pX < 7)
                        outb[(nt * 32 + mq) * 49 + pYv[mt] * 7 + pX] = f2bf(v);
                }
            }
        }
    }
}

// ---------------------------------------------------------------------------
// FC1 MFMA, 64-row blocks (R8/R9 version): partials[kh](B,128) = A @ W^T slice
// kh (K-split 7). A-tile staged in LDS; waves split N. Plain stores.
__global__ __launch_bounds__(256) void fc1_mfma(
    const unsigned short* __restrict__ A,
    const unsigned short* __restrict__ Wb,
    float* __restrict__ part, size_t PB) {  // PB = B*128
    __shared__ __align__(16) unsigned short As[64 * 72];  // stride 72 breaks banks
    const int blk = blockIdx.x;
    const int kh = blk % 7;
    const int m0 = (blk / 7) * 64;
    const int tid = threadIdx.x;
    const int wv = tid >> 6;
    const int lane = tid & 63;
    const int n16 = lane & 15;
    const int cig = lane >> 4;

    float4v acc[4][2];  // [mt][j]
#pragma unroll
    for (int mt = 0; mt < 4; ++mt)
#pragma unroll
        for (int j = 0; j < 2; ++j) acc[mt][j] = float4v{0.f, 0.f, 0.f, 0.f};

    for (int it = 0; it < 7; ++it) {
        int k0 = kh * 448 + it * 64;
        __syncthreads();
#pragma unroll
        for (int i = 0; i < 2; ++i) {
            int p = tid + 256 * i;         // 0..511 = 64 rows x 8 k-octs
            int r = p >> 3, ko = (p & 7) * 8;
            *(short8*)(As + r * 72 + ko) =
                *(const short8*)(A + (size_t)(m0 + r) * 3136 + k0 + ko);
        }
        __syncthreads();
#pragma unroll
        for (int h = 0; h < 2; ++h) {
            short8 af[4];
#pragma unroll
            for (int mt = 0; mt < 4; ++mt)
                af[mt] = *(const short8*)(As + (mt * 16 + n16) * 72 + h * 32 + cig * 8);
            short8 wf[2];
#pragma unroll
            for (int j = 0; j < 2; ++j)
                wf[j] = *(const short8*)(Wb + (size_t)((wv * 2 + j) * 16 + n16) * 3136 +
                                         k0 + h * 32 + cig * 8);
#pragma unroll
            for (int mt = 0; mt < 4; ++mt)
#pragma unroll
                for (int j = 0; j < 2; ++j)
                    acc[mt][j] = __builtin_amdgcn_mfma_f32_16x16x32_bf16(
                        af[mt], wf[j], acc[mt][j], 0, 0, 0);
        }
    }
    float* o = part + (size_t)kh * PB;
#pragma unroll
    for (int mt = 0; mt < 4; ++mt)
#pragma unroll
        for (int j = 0; j < 2; ++j)
#pragma unroll
            for (int r = 0; r < 4; ++r) {
                int row = m0 + mt * 16 + cig * 4 + r;
                o[(size_t)row * 128 + (wv * 2 + j) * 16 + n16] = acc[mt][j][r];
            }
}

// FC2 row-centric: thread (r,q) builds relu(sum of 7 partials + b1) for its
// 16-k slice ONCE (part read 1x, not 10x), dots vs all 10 W rows from LDS,
// shfl-xor(1,2,4) k-reduce. Block = 32 rows; grid B/32.
__global__ __launch_bounds__(256) void fc2_kernel(
    const float* __restrict__ part, size_t PB,
    const float* __restrict__ fc1b,
    const float* __restrict__ W, const float* __restrict__ bias,
    float* __restrict__ out) {
    __shared__ float smW[10 * 132];
    __shared__ float smB1[128];
    __shared__ float smB[10];
    int t = threadIdx.x;
    for (int i = t; i < 1280; i += 256) {
        int n = i >> 7, k = i & 127;
        smW[n * 132 + k] = W[i];
    }
    if (t < 128) smB1[t] = fc1b[t];
    if (t < 10) smB[t] = bias[t];
    __syncthreads();
    const int r = t >> 3;          // 0..31 (batch row in block)
    const int q = t & 7;           // 16-float k-slice
    const size_t b = (size_t)blockIdx.x * 32 + r;
    const float* pb = part + b * 128 + q * 16;

    float rv[16];
#pragma unroll
    for (int c = 0; c < 4; ++c) {
        float4 s = *(const float4*)(pb + 4 * c);
#pragma unroll
        for (int j = 1; j < 7; ++j) {
            float4 pj = *(const float4*)(pb + (size_t)j * PB + 4 * c);
            s.x += pj.x; s.y += pj.y; s.z += pj.z; s.w += pj.w;
        }
        float4 bv = *(const float4*)(smB1 + q * 16 + 4 * c);
        rv[4 * c + 0] = fmaxf(s.x + bv.x, 0.f);
        rv[4 * c + 1] = fmaxf(s.y + bv.y, 0.f);
        rv[4 * c + 2] = fmaxf(s.z + bv.z, 0.f);
        rv[4 * c + 3] = fmaxf(s.w + bv.w, 0.f);
    }
    float acc[10];
#pragma unroll
    for (int n = 0; n < 10; ++n) {
        const float4* wr = (const float4*)(smW + n * 132 + q * 16);
        float a = 0.f;
#pragma unroll
        for (int c = 0; c < 4; ++c) {
            float4 w = wr[c];
            a += rv[4 * c] * w.x + rv[4 * c + 1] * w.y +
                 rv[4 * c + 2] * w.z + rv[4 * c + 3] * w.w;
        }
        acc[n] = a;
    }
#pragma unroll
    for (int n = 0; n < 10; ++n) {
        acc[n] += __shfl_xor(acc[n], 1);
        acc[n] += __shfl_xor(acc[n], 2);
        acc[n] += __shfl_xor(acc[n], 4);
    }
    if (q == 0) {
#pragma unroll
        for (int n = 0; n < 10; ++n) out[b * 10 + n] = acc[n] + smB[n];
    }
}

extern "C" void kernel_launch(void* const* d_in, const int* in_sizes, int n_in,
                              void* d_out, int out_size, void* d_ws, size_t ws_size,
                              hipStream_t stream) {
    const float* x    = (const float*)d_in[0];
    const float* w1   = (const float*)d_in[1];
    const float* p1   = (const float*)d_in[2];
    const float* b1   = (const float*)d_in[3];
    const float* w2   = (const float*)d_in[4];
    const float* p2   = (const float*)d_in[5];
    const float* b2   = (const float*)d_in[6];
    const float* fc1w = (const float*)d_in[7];
    const float* fc1b = (const float*)d_in[8];
    const float* fc2w = (const float*)d_in[9];
    const float* fc2b = (const float*)d_in[10];
    float* out = (float*)d_out;

    const int B = in_sizes[0] / 784;  // 4096

    float* ws = (float*)d_ws;
    unsigned short* Kt  = (unsigned short*)ws;             // 51200 sh = 25600 f
    unsigned short* K1b = (unsigned short*)(ws + 25600);   // 2048 sh = 1024 f
    unsigned short* w1b = (unsigned short*)(ws + 26624);   // 401408 sh = 200704 f
    unsigned short* h2b = (unsigned short*)(ws + 227328);  // B*3136 sh = B*1568 f
    float* fc1p = ws + 227328 + (size_t)B * 1568;          // 7*B*128 f

    prep_all<<<404, 256, 0, stream>>>(w1, p1, w2, p2, fc1w, K1b, Kt, w1b);
    fused_conv_mfma<<<B, 256, 0, stream>>>(x, K1b, Kt, b1, b2, h2b);
    fc1_mfma<<<(B / 64) * 7, 256, 0, stream>>>(h2b, w1b, fc1p, (size_t)B * 128);
    fc2_kernel<<<B / 32, 256, 0, stream>>>(fc1p, (size_t)B * 128,
                                           fc1b, fc2w, fc2b, out);
}